// Round 4
// baseline (1817.517 us; speedup 1.0000x reference)
//
#include <hip/hip_runtime.h>

// DubinsLSTM R4: MFMA restructure.
// 2-layer LSTM H=128, T=200, B=1024. EPB=16 elements/block, grid=64, 512 thr.
// Per step: z = A(16xK) @ W(Kx512) via v_mfma_f32_16x16x32_f16.
// Wave w owns N-tiles {w,8+w,16+w,24+w} = all 4 gates of units 16w..16w+15,
// so gate update is lane-local (C/D: row=(l>>4)*4+r = batch m, col=l&15 = unit).
// Weights live in d_ws in fragment-linear f16 order -> coalesced dwordx4 from
// L2, zero LDS for B. A (h-state) is one padded [16][264] f16 LDS tile:
// 12 ds_read_b128 per wave per step (vs 1536 broadcast reads in R3).

#define BB 1024
#define TT 200
#define INDIM 3
#define CDIM 4
#define HH 128
#define OD 3
#define GG 512
#define EPB 16
#define LDA 264              // padded A row stride (halves): 528B = 33*16 ✓
#define W1F_OFF 65536        // halves
#define WF_TOTAL 196608      // halves (384 KB)

typedef _Float16 f16x8 __attribute__((ext_vector_type(8)));
typedef _Float16 f16x4 __attribute__((ext_vector_type(4)));
typedef float f32x4 __attribute__((ext_vector_type(4)));

__device__ __forceinline__ float sigf(float x) {
    return __fdividef(1.f, 1.f + __expf(-x));
}
// safe fast tanh: 1 - 2/(e^{2x}+1); handles +-inf correctly
__device__ __forceinline__ float tanhfast(float x) {
    return 1.f - __fdividef(2.f, __expf(2.f * x) + 1.f);
}

// Repack Whh0 / [Wih1;Whh1] into MFMA-B fragment-linear f16:
//   frag(nt, ks): lane l holds B[k = ks*32 + 8*(l>>4) + j][col = nt*16 + (l&15)], j=0..7
//   W0f: 32 nt x 4 ks;  W1f: 32 nt x 8 ks.
__global__ void repack_frag_kernel(const float* __restrict__ Whh0,
                                   const float* __restrict__ Wih1,
                                   const float* __restrict__ Whh1,
                                   _Float16* __restrict__ wf) {
    int idx = blockIdx.x * 256 + threadIdx.x;   // 0..196607
    if (idx < 65536) {
        int nt = idx >> 11;            // 2048 halves per nt (4*64*8)
        int ks = (idx >> 9) & 3;
        int l  = (idx >> 3) & 63;
        int j  = idx & 7;
        int k  = ks * 32 + ((l >> 4) << 3) + j;
        int col = nt * 16 + (l & 15);
        wf[idx] = (_Float16)Whh0[k * GG + col];
    } else {
        int i2 = idx - 65536;
        int nt = i2 >> 12;             // 4096 halves per nt (8*64*8)
        int ks = (i2 >> 9) & 7;
        int l  = (i2 >> 3) & 63;
        int j  = i2 & 7;
        int k  = ks * 32 + ((l >> 4) << 3) + j;
        int col = nt * 16 + (l & 15);
        float v = (k < HH) ? Wih1[k * GG + col] : Whh1[(k - HH) * GG + col];
        wf[idx] = (_Float16)v;
    }
}

__global__ __launch_bounds__(512, 2) void dubins_lstm_mfma_kernel(
    const float* __restrict__ conds,       // [B,4]
    const float* __restrict__ target_seq,  // [B,T,3]
    const int*   __restrict__ lengths,     // [B]
    const float* __restrict__ tf_rand,     // [T,B]
    const float* __restrict__ Wc,          // [4,128]
    const float* __restrict__ bc,          // [128]
    const float* __restrict__ Wih0,        // [131,512] fp32 (pre-loop + prev rows)
    const float* __restrict__ b0,          // [512]
    const float* __restrict__ b1,          // [512]
    const float* __restrict__ Wo,          // [128,3]
    const float* __restrict__ bo,          // [3]
    const _Float16* __restrict__ wf,       // fragment-linear f16 weights
    float* __restrict__ out)               // [B,T,3]
{
    __shared__ _Float16 A[EPB][LDA];   // cols 0..127: h0, 128..255: h1 (8.25KB)
    __shared__ float prevs[EPB][4];
    __shared__ float cemb[EPB][HH];    // f32, pre-loop only (8KB)

    const int tid  = threadIdx.x;
    const int w    = tid >> 6;     // wave 0..7
    const int l    = tid & 63;
    const int lo16 = l & 15;
    const int lhi  = l >> 4;       // 0..3
    const int b_base = blockIdx.x * EPB;

    // ---- init LDS ----
    {
        _Float16* Af = &A[0][0];
        for (int i = tid; i < EPB * LDA; i += 512) Af[i] = (_Float16)0.f;
        if (tid < EPB * 4) ((float*)prevs)[tid] = 0.f;
    }

    // ---- cemb[m][k] = bc[k] + conds[m,:] @ Wc  (4 k's per thread) ----
    {
        int m  = tid >> 5;
        int k0 = (tid & 31) * 4;
        float cd[CDIM];
        #pragma unroll
        for (int d = 0; d < CDIM; ++d) cd[d] = conds[(b_base + m) * CDIM + d];
        #pragma unroll
        for (int kk = 0; kk < 4; ++kk) {
            int k = k0 + kk;
            float v = bc[k];
            #pragma unroll
            for (int d = 0; d < CDIM; ++d) v = fmaf(cd[d], Wc[d * HH + k], v);
            cemb[m][k] = v;
        }
    }

    // ---- per-lane constants ----
    float wprev[4][3];   // Wih0[0:3][col_q]
    float b1c[4];
    f32x4 cz[4];         // time-invariant C-init: b0[col] + cemb @ Wih0[3:]
    int colq[4];
    #pragma unroll
    for (int q = 0; q < 4; ++q) {
        colq[q] = (w + 8 * q) * 16 + lo16;
        b1c[q] = b1[colq[q]];
        #pragma unroll
        for (int d = 0; d < 3; ++d) wprev[q][d] = Wih0[d * GG + colq[q]];
        float bz = b0[colq[q]];
        cz[q] = {bz, bz, bz, bz};
    }

    // output-projection role
    const int om = tid >> 5;      // element m, 0..15
    const int pl = tid & 31;
    const int plen = lengths[b_base + om];
    float wod[4][3];
    #pragma unroll
    for (int i = 0; i < 4; ++i)
        #pragma unroll
        for (int d = 0; d < 3; ++d) wod[i][d] = Wo[(pl * 4 + i) * OD + d];
    const float bod[3] = {bo[0], bo[1], bo[2]};

    __syncthreads();   // cemb / A / prevs ready

    // ---- cz += cemb[m,:] @ Wih0[3+k][col_q]  (once) ----
    for (int k = 0; k < HH; ++k) {
        float cv0 = cemb[lhi * 4 + 0][k];
        float cv1 = cemb[lhi * 4 + 1][k];
        float cv2 = cemb[lhi * 4 + 2][k];
        float cv3 = cemb[lhi * 4 + 3][k];
        #pragma unroll
        for (int q = 0; q < 4; ++q) {
            float wv = Wih0[(INDIM + k) * GG + colq[q]];
            cz[q][0] = fmaf(cv0, wv, cz[q][0]);
            cz[q][1] = fmaf(cv1, wv, cz[q][1]);
            cz[q][2] = fmaf(cv2, wv, cz[q][2]);
            cz[q][3] = fmaf(cv3, wv, cz[q][3]);
        }
    }

    // fragment pointers
    const f16x8* __restrict__ apRow  = reinterpret_cast<const f16x8*>(&A[lo16][0]);
    const f16x8* __restrict__ w0base = reinterpret_cast<const f16x8*>(wf) + (w * 256 + l);
    const f16x8* __restrict__ w1base = reinterpret_cast<const f16x8*>(wf + W1F_OFF) + (w * 512 + l);

    float c0s[4] = {0.f, 0.f, 0.f, 0.f};
    float c1s[4] = {0.f, 0.f, 0.f, 0.f};

    for (int t = 0; t < TT; ++t) {
        f32x4 acc[4];

        // ---- P0: layer-0  z = cz + prev@Wp + h0old@Whh0 ----
        #pragma unroll
        for (int q = 0; q < 4; ++q) acc[q] = cz[q];
        #pragma unroll
        for (int r = 0; r < 4; ++r) {
            const float4 pv = *reinterpret_cast<const float4*>(&prevs[lhi * 4 + r][0]);
            #pragma unroll
            for (int q = 0; q < 4; ++q)
                acc[q][r] = fmaf(pv.z, wprev[q][2],
                            fmaf(pv.y, wprev[q][1],
                            fmaf(pv.x, wprev[q][0], acc[q][r])));
        }
        #pragma unroll
        for (int ks = 0; ks < 4; ++ks) {
            const f16x8 a = apRow[ks * 4 + lhi];
            #pragma unroll
            for (int q = 0; q < 4; ++q)
                acc[q] = __builtin_amdgcn_mfma_f32_16x16x32_f16(
                             a, w0base[q * 2048 + ks * 64], acc[q], 0, 0, 0);
        }
        __syncthreads();   // bar1: all h0-old reads done

        // ---- P1: gate-0, write h0new ----
        #pragma unroll
        for (int r = 0; r < 4; ++r) {
            const float zi = acc[0][r], zf = acc[1][r], zg = acc[2][r], zo = acc[3][r];
            c0s[r] = sigf(zf) * c0s[r] + sigf(zi) * tanhfast(zg);
            A[lhi * 4 + r][w * 16 + lo16] = (_Float16)(sigf(zo) * tanhfast(c0s[r]));
        }
        __syncthreads();   // bar2: h0new visible

        // ---- P2: layer-1  z = b1 + [h0new;h1old] @ W1 ----
        #pragma unroll
        for (int q = 0; q < 4; ++q) acc[q] = {b1c[q], b1c[q], b1c[q], b1c[q]};
        #pragma unroll
        for (int ks = 0; ks < 8; ++ks) {
            const f16x8 a = apRow[ks * 4 + lhi];
            #pragma unroll
            for (int q = 0; q < 4; ++q)
                acc[q] = __builtin_amdgcn_mfma_f32_16x16x32_f16(
                             a, w1base[q * 4096 + ks * 64], acc[q], 0, 0, 0);
        }
        __syncthreads();   // bar3: all h1-old reads done

        // ---- P3: gate-1, write h1new ----
        #pragma unroll
        for (int r = 0; r < 4; ++r) {
            const float zi = acc[0][r], zf = acc[1][r], zg = acc[2][r], zo = acc[3][r];
            c1s[r] = sigf(zf) * c1s[r] + sigf(zi) * tanhfast(zg);
            A[lhi * 4 + r][HH + w * 16 + lo16] = (_Float16)(sigf(zo) * tanhfast(c1s[r]));
        }
        __syncthreads();   // bar4: h1new visible

        // ---- P4: output projection + teacher forcing ----
        {
            const f16x4 hv = *reinterpret_cast<const f16x4*>(&A[om][HH + pl * 4]);
            const float h0_ = (float)hv[0], h1_ = (float)hv[1],
                        h2_ = (float)hv[2], h3_ = (float)hv[3];
            const int bg = b_base + om;
            bool use_tf = false;
            if (pl == 0) use_tf = (tf_rand[t * BB + bg] < 0.5f) && (t < plen);
            #pragma unroll
            for (int d = 0; d < 3; ++d) {
                float s = h0_ * wod[0][d];
                s = fmaf(h1_, wod[1][d], s);
                s = fmaf(h2_, wod[2][d], s);
                s = fmaf(h3_, wod[3][d], s);
                s += __shfl_xor(s, 16, 32);
                s += __shfl_xor(s, 8, 32);
                s += __shfl_xor(s, 4, 32);
                s += __shfl_xor(s, 2, 32);
                s += __shfl_xor(s, 1, 32);
                if (pl == 0) {
                    const float pred = s + bod[d];
                    out[(bg * TT + t) * OD + d] = pred;
                    prevs[om][d] = use_tf ? target_seq[(bg * TT + t) * OD + d] : pred;
                }
            }
        }
        __syncthreads();   // bar5: prevs ready for next step
    }
}

extern "C" void kernel_launch(void* const* d_in, const int* in_sizes, int n_in,
                              void* d_out, int out_size, void* d_ws, size_t ws_size,
                              hipStream_t stream) {
    const float* conds   = (const float*)d_in[0];
    const float* target  = (const float*)d_in[1];
    const int*   lengths = (const int*)d_in[2];
    const float* tfr     = (const float*)d_in[3];
    const float* Wc      = (const float*)d_in[4];
    const float* bc      = (const float*)d_in[5];
    const float* Wih0    = (const float*)d_in[6];
    const float* Whh0    = (const float*)d_in[7];
    const float* b0      = (const float*)d_in[8];
    const float* Wih1    = (const float*)d_in[9];
    const float* Whh1    = (const float*)d_in[10];
    const float* b1      = (const float*)d_in[11];
    const float* Wo      = (const float*)d_in[12];
    const float* bo      = (const float*)d_in[13];
    float* out = (float*)d_out;
    _Float16* wf = (_Float16*)d_ws;

    repack_frag_kernel<<<WF_TOTAL / 256, 256, 0, stream>>>(Whh0, Wih1, Whh1, wf);
    dubins_lstm_mfma_kernel<<<BB / EPB, 512, 0, stream>>>(
        conds, target, lengths, tfr, Wc, bc,
        Wih0, b0, b1, Wo, bo, wf, out);
}

// Round 5
// 1661.849 us; speedup vs baseline: 1.0937x; 1.0937x over previous
//
#include <hip/hip_runtime.h>

// DubinsLSTM R5: register-resident weights + double-buffered h-state.
// R4 failed because 384KB of weight fragments streamed global->VGPR every
// step through a 128-VGPR budget -> ~48 serialized L2 loads/step (~20k cy).
// R5: 43/48 B-frags pinned in VGPRs for the whole t-loop (asm pin defeats
// load rematerialization); 5 frags/wave in LDS (re-read per step, hidden).
// A-tile double-buffered -> 3 barriers/step. Step latency ~1.7k cy.

#define BB 1024
#define TT 200
#define INDIM 3
#define CDIM 4
#define HH 128
#define OD 3
#define GG 512
#define EPB 16
#define LDA 264              // halves; 528B row stride, 16B aligned
#define W1F_OFF 65536        // halves
#define WF_TOTAL 196608      // halves (384 KB)

// smem blob: A0 [16][264] f16 (8448B) | A1 (8448B) | wlds 5*8*64*16B (40960B)
#define A1_OFF   8448
#define WLDS_OFF 16896
#define SMEM_SZ  57856

typedef _Float16 f16x8 __attribute__((ext_vector_type(8)));
typedef _Float16 f16x4 __attribute__((ext_vector_type(4)));
typedef float f32x4 __attribute__((ext_vector_type(4)));

__device__ __forceinline__ float sigf(float x) {
    return __fdividef(1.f, 1.f + __expf(-x));
}
__device__ __forceinline__ float tanhfast(float x) {
    return 1.f - __fdividef(2.f, __expf(2.f * x) + 1.f);
}
__device__ __forceinline__ void pin4(uint4& v) {
    asm volatile("" : "+v"(v.x), "+v"(v.y), "+v"(v.z), "+v"(v.w));
}

// Repack Whh0 / [Wih1;Whh1] into MFMA-B fragment-linear f16 (same as R4):
// frag(nt,ks): lane l holds B[k=ks*32+8*(l>>4)+j][col=nt*16+(l&15)], j=0..7
__global__ void repack_frag_kernel(const float* __restrict__ Whh0,
                                   const float* __restrict__ Wih1,
                                   const float* __restrict__ Whh1,
                                   _Float16* __restrict__ wf) {
    int idx = blockIdx.x * 256 + threadIdx.x;
    if (idx < 65536) {
        int nt = idx >> 11;
        int ks = (idx >> 9) & 3;
        int l  = (idx >> 3) & 63;
        int j  = idx & 7;
        int k  = ks * 32 + ((l >> 4) << 3) + j;
        int col = nt * 16 + (l & 15);
        wf[idx] = (_Float16)Whh0[k * GG + col];
    } else {
        int i2 = idx - 65536;
        int nt = i2 >> 12;
        int ks = (i2 >> 9) & 7;
        int l  = (i2 >> 3) & 63;
        int j  = i2 & 7;
        int k  = ks * 32 + ((l >> 4) << 3) + j;
        int col = nt * 16 + (l & 15);
        float v = (k < HH) ? Wih1[k * GG + col] : Whh1[(k - HH) * GG + col];
        wf[idx] = (_Float16)v;
    }
}

__global__ __launch_bounds__(512, 2) void dubins_lstm_mfma_kernel(
    const float* __restrict__ conds,
    const float* __restrict__ target_seq,
    const int*   __restrict__ lengths,
    const float* __restrict__ tf_rand,
    const float* __restrict__ Wc,
    const float* __restrict__ bc,
    const float* __restrict__ Wih0,
    const float* __restrict__ b0,
    const float* __restrict__ b1,
    const float* __restrict__ Wo,
    const float* __restrict__ bo,
    const _Float16* __restrict__ wf,
    float* __restrict__ out)
{
    __shared__ __align__(16) unsigned char smem[SMEM_SZ];
    __shared__ float prevs[EPB][4];

    _Float16* A0 = (_Float16*)smem;
    _Float16* A1 = (_Float16*)(smem + A1_OFF);
    uint4*    wldsU = (uint4*)(smem + WLDS_OFF);
    float*    cembL = (float*)(smem + WLDS_OFF);   // alias: pre-loop only

    const int tid  = threadIdx.x;
    const int w    = tid >> 6;
    const int l    = tid & 63;
    const int lo16 = l & 15;
    const int lhi  = l >> 4;
    const int b_base = blockIdx.x * EPB;
    const int om = tid >> 5;       // P4 element
    const int pl = tid & 31;       // P4 lane

    // ---- zero both A buffers + prevs ----
    for (int i = tid; i < 4224; i += 512) ((unsigned int*)smem)[i] = 0u;
    if (tid < EPB * 4) ((float*)prevs)[tid] = 0.f;

    // ---- cemb[m][k] (f32, aliased LDS) ----
    {
        int m  = tid >> 5;
        int k0 = (tid & 31) * 4;
        float cd[CDIM];
        #pragma unroll
        for (int d = 0; d < CDIM; ++d) cd[d] = conds[(b_base + m) * CDIM + d];
        #pragma unroll
        for (int kk = 0; kk < 4; ++kk) {
            int k = k0 + kk;
            float v = bc[k];
            #pragma unroll
            for (int d = 0; d < CDIM; ++d) v = fmaf(cd[d], Wc[d * HH + k], v);
            cembL[m * HH + k] = v;
        }
    }
    __syncthreads();

    // ---- per-lane constants ----
    int colq[4]; float b1c[4]; float wprev[4][3]; f32x4 cz[4];
    #pragma unroll
    for (int q = 0; q < 4; ++q) {
        colq[q] = (w + 8 * q) * 16 + lo16;
        b1c[q] = b1[colq[q]];
        #pragma unroll
        for (int d = 0; d < 3; ++d) wprev[q][d] = Wih0[d * GG + colq[q]];
        float bz = b0[colq[q]];
        cz[q] = {bz, bz, bz, bz};
    }
    for (int k = 0; k < HH; ++k) {
        float cv0 = cembL[(lhi * 4 + 0) * HH + k];
        float cv1 = cembL[(lhi * 4 + 1) * HH + k];
        float cv2 = cembL[(lhi * 4 + 2) * HH + k];
        float cv3 = cembL[(lhi * 4 + 3) * HH + k];
        #pragma unroll
        for (int q = 0; q < 4; ++q) {
            float wv = Wih0[(INDIM + k) * GG + colq[q]];
            cz[q][0] = fmaf(cv0, wv, cz[q][0]);
            cz[q][1] = fmaf(cv1, wv, cz[q][1]);
            cz[q][2] = fmaf(cv2, wv, cz[q][2]);
            cz[q][3] = fmaf(cv3, wv, cz[q][3]);
        }
    }
    const float bov  = (pl < OD) ? bo[pl] : 0.f;
    const int   plen = lengths[b_base + om];

    // ---- load weight fragments into registers (pinned) ----
    const uint4* __restrict__ w0g = reinterpret_cast<const uint4*>(wf) + (w * 256 + l);
    const uint4* __restrict__ w1g = reinterpret_cast<const uint4*>(wf + W1F_OFF) + (w * 512 + l);
    uint4 w0r[16];   // layer-0: f = ks*4+q
    uint4 w1r[27];   // layer-1: f = ks*4+q, f<27 in regs, f>=27 in LDS
    #pragma unroll
    for (int f = 0; f < 16; ++f) {
        int ks = f >> 2, q = f & 3;
        w0r[f] = w0g[q * 2048 + ks * 64];
        pin4(w0r[f]);
    }
    #pragma unroll
    for (int f = 0; f < 27; ++f) {
        int ks = f >> 2, q = f & 3;
        w1r[f] = w1g[q * 4096 + ks * 64];
        pin4(w1r[f]);
    }
    __syncthreads();   // cemb reads done before wlds overwrite

    // ---- spill frags f=27..31 to LDS (per-wave contiguous) ----
    #pragma unroll
    for (int fi = 0; fi < 5; ++fi) {
        int f = 27 + fi, ks = f >> 2, q = f & 3;
        wldsU[(w * 5 + fi) * 64 + l] = w1g[q * 4096 + ks * 64];
    }
    __syncthreads();

    float c0s[4] = {0.f, 0.f, 0.f, 0.f};
    float c1s[4] = {0.f, 0.f, 0.f, 0.f};

    for (int t = 0; t < TT; ++t) {
        _Float16* Ac = (t & 1) ? A1 : A0;   // current (read h-old)
        _Float16* An = (t & 1) ? A0 : A1;   // next (write h-new)
        const f16x8* apC = reinterpret_cast<const f16x8*>(Ac + lo16 * LDA);
        const f16x8* apN = reinterpret_cast<const f16x8*>(An + lo16 * LDA);

        // prefetch per-step inputs (independent of compute)
        const float tfv = tf_rand[t * BB + b_base + om];
        float tgtv = 0.f;
        if (pl < OD) tgtv = target_seq[((b_base + om) * TT + t) * OD + pl];

        // LDS spill-frags (static content; latency hides under P0)
        uint4 wl[5];
        #pragma unroll
        for (int fi = 0; fi < 5; ++fi) wl[fi] = wldsU[(w * 5 + fi) * 64 + l];

        f32x4 acc[4];

        // ---- P0: z0 = cz + prev@Wp + h0old@Whh0 ----
        #pragma unroll
        for (int q = 0; q < 4; ++q) acc[q] = cz[q];
        #pragma unroll
        for (int r = 0; r < 4; ++r) {
            const float4 pv = *reinterpret_cast<const float4*>(&prevs[lhi * 4 + r][0]);
            #pragma unroll
            for (int q = 0; q < 4; ++q)
                acc[q][r] = fmaf(pv.z, wprev[q][2],
                            fmaf(pv.y, wprev[q][1],
                            fmaf(pv.x, wprev[q][0], acc[q][r])));
        }
        #pragma unroll
        for (int ks = 0; ks < 4; ++ks) {
            const f16x8 a = apC[ks * 4 + lhi];
            #pragma unroll
            for (int q = 0; q < 4; ++q)
                acc[q] = __builtin_amdgcn_mfma_f32_16x16x32_f16(
                             a, __builtin_bit_cast(f16x8, w0r[ks * 4 + q]), acc[q], 0, 0, 0);
        }

        // ---- P1: gate-0 (lane-local), write h0new -> An ----
        #pragma unroll
        for (int r = 0; r < 4; ++r) {
            const float zi = acc[0][r], zf = acc[1][r], zg = acc[2][r], zo = acc[3][r];
            c0s[r] = sigf(zf) * c0s[r] + sigf(zi) * tanhfast(zg);
            An[(lhi * 4 + r) * LDA + w * 16 + lo16] = (_Float16)(sigf(zo) * tanhfast(c0s[r]));
        }
        __syncthreads();   // bar_a: h0new visible

        // ---- P2: z1 = b1 + [h0new ; h1old] @ W1 ----
        #pragma unroll
        for (int q = 0; q < 4; ++q) acc[q] = {b1c[q], b1c[q], b1c[q], b1c[q]};
        #pragma unroll
        for (int ks = 0; ks < 8; ++ks) {
            const f16x8 a = (ks < 4) ? apN[ks * 4 + lhi]
                                     : apC[16 + (ks - 4) * 4 + lhi];
            #pragma unroll
            for (int q = 0; q < 4; ++q) {
                const int f = ks * 4 + q;
                const f16x8 b = __builtin_bit_cast(f16x8, (f < 27) ? w1r[f] : wl[f - 27]);
                acc[q] = __builtin_amdgcn_mfma_f32_16x16x32_f16(a, b, acc[q], 0, 0, 0);
            }
        }

        // ---- P3: gate-1 (lane-local), write h1new -> An ----
        #pragma unroll
        for (int r = 0; r < 4; ++r) {
            const float zi = acc[0][r], zf = acc[1][r], zg = acc[2][r], zo = acc[3][r];
            c1s[r] = sigf(zf) * c1s[r] + sigf(zi) * tanhfast(zg);
            An[(lhi * 4 + r) * LDA + HH + w * 16 + lo16] = (_Float16)(sigf(zo) * tanhfast(c1s[r]));
        }
        __syncthreads();   // bar_b: h1new visible

        // ---- P4: output projection + teacher forcing ----
        {
            float wodv[12];
            #pragma unroll
            for (int i = 0; i < 4; ++i)
                #pragma unroll
                for (int d = 0; d < 3; ++d) wodv[i * 3 + d] = Wo[(pl * 4 + i) * OD + d];
            const f16x4 hv = *reinterpret_cast<const f16x4*>(An + om * LDA + HH + pl * 4);
            const float h0_ = (float)hv[0], h1_ = (float)hv[1],
                        h2_ = (float)hv[2], h3_ = (float)hv[3];
            float s0 = fmaf(h3_, wodv[9],  fmaf(h2_, wodv[6], fmaf(h1_, wodv[3], h0_ * wodv[0])));
            float s1 = fmaf(h3_, wodv[10], fmaf(h2_, wodv[7], fmaf(h1_, wodv[4], h0_ * wodv[1])));
            float s2 = fmaf(h3_, wodv[11], fmaf(h2_, wodv[8], fmaf(h1_, wodv[5], h0_ * wodv[2])));
            #pragma unroll
            for (int sh = 16; sh >= 1; sh >>= 1) {
                s0 += __shfl_xor(s0, sh, 32);
                s1 += __shfl_xor(s1, sh, 32);
                s2 += __shfl_xor(s2, sh, 32);
            }
            if (pl < OD) {
                const float sv = (pl == 0) ? s0 : (pl == 1) ? s1 : s2;
                const float pred = sv + bov;
                const int bg = b_base + om;
                out[(bg * TT + t) * OD + pl] = pred;
                const bool use_tf = (tfv < 0.5f) && (t < plen);
                prevs[om][pl] = use_tf ? tgtv : pred;
            }
        }
        __syncthreads();   // bar_c: prevs ready for next step
    }
}

extern "C" void kernel_launch(void* const* d_in, const int* in_sizes, int n_in,
                              void* d_out, int out_size, void* d_ws, size_t ws_size,
                              hipStream_t stream) {
    const float* conds   = (const float*)d_in[0];
    const float* target  = (const float*)d_in[1];
    const int*   lengths = (const int*)d_in[2];
    const float* tfr     = (const float*)d_in[3];
    const float* Wc      = (const float*)d_in[4];
    const float* bc      = (const float*)d_in[5];
    const float* Wih0    = (const float*)d_in[6];
    const float* Whh0    = (const float*)d_in[7];
    const float* b0      = (const float*)d_in[8];
    const float* Wih1    = (const float*)d_in[9];
    const float* Whh1    = (const float*)d_in[10];
    const float* b1      = (const float*)d_in[11];
    const float* Wo      = (const float*)d_in[12];
    const float* bo      = (const float*)d_in[13];
    float* out = (float*)d_out;
    _Float16* wf = (_Float16*)d_ws;

    repack_frag_kernel<<<WF_TOTAL / 256, 256, 0, stream>>>(Whh0, Wih1, Whh1, wf);
    dubins_lstm_mfma_kernel<<<BB / EPB, 512, 0, stream>>>(
        conds, target, lengths, tfr, Wc, bc,
        Wih0, b0, b1, Wo, bo, wf, out);
}

// Round 7
// 1356.090 us; speedup vs baseline: 1.3403x; 1.2255x over previous
//
#include <hip/hip_runtime.h>

// DubinsLSTM R7: fix R6's czT wave-sharing bug (cz is wave-dependent; the
// LDS table had no wave index -> 8 waves stomped each other, absmax 0.164).
// cz now lives per-thread in registers, packed f16 (8 VGPRs vs R5's 16 f32).
// LDS frags read just-in-time in P2 (no wl[5] staging: -20 transient VGPRs).
// amdgpu_waves_per_eu(2,2) pins occupancy so the RA gets the full 256-VGPR
// budget (R4/R5 signature: VGPR=128 + ~88 scratch slots, WRITE_SIZE 14MB).

#define BB 1024
#define TT 200
#define INDIM 3
#define CDIM 4
#define HH 128
#define OD 3
#define GG 512
#define EPB 16
#define LDA 264              // halves; 528B row stride
#define W1F_OFF 65536        // halves
#define WF_TOTAL 196608      // halves (384 KB)

// smem blob (bytes):
#define A1_OFF    8448       // A0 [16][264] f16
#define WLDS_OFF  16896      // 5 frags x 8 waves x 64 lanes x 16B = 40960
#define B1T_OFF   57856      // b1t [8][4][16] f32 = 2048
#define WOT_OFF   59904      // WoT [3][128] f32 = 1536
#define PREVS_OFF 61440      // prevs [16][4] f32 = 256
#define SMEM_SZ   61696

typedef _Float16 f16x8 __attribute__((ext_vector_type(8)));
typedef _Float16 f16x4 __attribute__((ext_vector_type(4)));
typedef float f32x4 __attribute__((ext_vector_type(4)));

__device__ __forceinline__ float sigf(float x) {
    return __fdividef(1.f, 1.f + __expf(-x));
}
__device__ __forceinline__ float tanhfast(float x) {
    return 1.f - __fdividef(2.f, __expf(2.f * x) + 1.f);
}
__device__ __forceinline__ void pin4(uint4& v) {
    asm volatile("" : "+v"(v.x), "+v"(v.y), "+v"(v.z), "+v"(v.w));
}

// Repack Whh0 / [Wih1;Whh1] into MFMA-B fragment-linear f16 (layout verified
// R4/R5): frag(nt,ks): lane l holds B[k=ks*32+8*(l>>4)+j][col=nt*16+(l&15)].
__global__ void repack_frag_kernel(const float* __restrict__ Whh0,
                                   const float* __restrict__ Wih1,
                                   const float* __restrict__ Whh1,
                                   _Float16* __restrict__ wf) {
    int idx = blockIdx.x * 256 + threadIdx.x;
    if (idx < 65536) {
        int nt = idx >> 11;
        int ks = (idx >> 9) & 3;
        int l  = (idx >> 3) & 63;
        int j  = idx & 7;
        int k  = ks * 32 + ((l >> 4) << 3) + j;
        int col = nt * 16 + (l & 15);
        wf[idx] = (_Float16)Whh0[k * GG + col];
    } else {
        int i2 = idx - 65536;
        int nt = i2 >> 12;
        int ks = (i2 >> 9) & 7;
        int l  = (i2 >> 3) & 63;
        int j  = i2 & 7;
        int k  = ks * 32 + ((l >> 4) << 3) + j;
        int col = nt * 16 + (l & 15);
        float v = (k < HH) ? Wih1[k * GG + col] : Whh1[(k - HH) * GG + col];
        wf[idx] = (_Float16)v;
    }
}

__global__ __attribute__((amdgpu_waves_per_eu(2, 2)))
__launch_bounds__(512) void dubins_lstm_mfma_kernel(
    const float* __restrict__ conds,
    const float* __restrict__ target_seq,
    const int*   __restrict__ lengths,
    const float* __restrict__ tf_rand,
    const float* __restrict__ Wc,
    const float* __restrict__ bc,
    const float* __restrict__ Wih0,
    const float* __restrict__ b0,
    const float* __restrict__ b1,
    const float* __restrict__ Wo,
    const float* __restrict__ bo,
    const _Float16* __restrict__ wf,
    float* __restrict__ out)
{
    __shared__ __align__(16) unsigned char smem[SMEM_SZ];
    _Float16* A0    = (_Float16*)smem;
    _Float16* A1    = (_Float16*)(smem + A1_OFF);
    uint4*    wldsU = (uint4*)(smem + WLDS_OFF);
    float*    cembL = (float*)(smem + WLDS_OFF);    // alias: pre-loop only
    float*    b1t   = (float*)(smem + B1T_OFF);     // [w][q][u]
    float*    WoT   = (float*)(smem + WOT_OFF);     // [d][k]
    float*    prevs = (float*)(smem + PREVS_OFF);   // [m][4]

    const int tid  = threadIdx.x;
    const int w    = tid >> 6;
    const int l    = tid & 63;
    const int lo16 = l & 15;
    const int lhi  = l >> 4;
    const int b_base = blockIdx.x * EPB;
    const int om = tid >> 5;       // P4 element
    const int pl = tid & 31;       // P4 lane

    // ---- zero A0+A1, prevs; fill b1t, WoT ----
    for (int i = tid; i < 4224; i += 512) ((unsigned int*)smem)[i] = 0u;
    if (tid < 64) prevs[tid] = 0.f;
    {   // b1t[w][q][u] = b1[(w+8q)*16+u]
        int fw = tid >> 6, fq = (tid >> 4) & 3, fu = tid & 15;
        b1t[tid] = b1[(fw + 8 * fq) * 16 + fu];
    }
    if (tid < 384) WoT[(tid % 3) * 128 + tid / 3] = Wo[tid];

    // ---- cemb[m][k] (f32, aliased LDS) ----
    {
        int m  = tid >> 5;
        int k0 = (tid & 31) * 4;
        float cd[CDIM];
        #pragma unroll
        for (int d = 0; d < CDIM; ++d) cd[d] = conds[(b_base + m) * CDIM + d];
        #pragma unroll
        for (int kk = 0; kk < 4; ++kk) {
            int k = k0 + kk;
            float v = bc[k];
            #pragma unroll
            for (int d = 0; d < CDIM; ++d) v = fmaf(cd[d], Wc[d * HH + k], v);
            cembL[m * HH + k] = v;
        }
    }
    __syncthreads();

    // ---- cz (time-invariant C-init) -> per-thread packed f16 regs ----
    f16x4 czp[4];
    {
        f32x4 cz[4];
        int colq[4];
        #pragma unroll
        for (int q = 0; q < 4; ++q) {
            colq[q] = (w + 8 * q) * 16 + lo16;
            float bz = b0[colq[q]];
            cz[q] = {bz, bz, bz, bz};
        }
        for (int k = 0; k < HH; ++k) {
            float cv0 = cembL[(lhi * 4 + 0) * HH + k];
            float cv1 = cembL[(lhi * 4 + 1) * HH + k];
            float cv2 = cembL[(lhi * 4 + 2) * HH + k];
            float cv3 = cembL[(lhi * 4 + 3) * HH + k];
            #pragma unroll
            for (int q = 0; q < 4; ++q) {
                float wv = Wih0[(INDIM + k) * GG + colq[q]];
                cz[q][0] = fmaf(cv0, wv, cz[q][0]);
                cz[q][1] = fmaf(cv1, wv, cz[q][1]);
                cz[q][2] = fmaf(cv2, wv, cz[q][2]);
                cz[q][3] = fmaf(cv3, wv, cz[q][3]);
            }
        }
        #pragma unroll
        for (int q = 0; q < 4; ++q)
            #pragma unroll
            for (int r = 0; r < 4; ++r) czp[q][r] = (_Float16)cz[q][r];
        __syncthreads();   // cembL reads done; wlds region may be overwritten
    }

    // ---- wprev (12 loop-invariant regs) ----
    float wprev[4][3];
    #pragma unroll
    for (int q = 0; q < 4; ++q)
        #pragma unroll
        for (int d = 0; d < 3; ++d) wprev[q][d] = Wih0[d * GG + (w + 8 * q) * 16 + lo16];
    const float bov  = (pl < OD) ? bo[pl] : 0.f;
    const int   plen = lengths[b_base + om];

    // ---- weight fragments -> registers (pinned) + 5 frags -> LDS ----
    const uint4* __restrict__ w0g = reinterpret_cast<const uint4*>(wf) + (w * 256 + l);
    const uint4* __restrict__ w1g = reinterpret_cast<const uint4*>(wf + W1F_OFF) + (w * 512 + l);
    uint4 w0r[16];
    uint4 w1r[27];
    #pragma unroll
    for (int f = 0; f < 16; ++f) {
        int ks = f >> 2, q = f & 3;
        w0r[f] = w0g[q * 2048 + ks * 64];
        pin4(w0r[f]);
    }
    #pragma unroll
    for (int f = 0; f < 27; ++f) {
        int ks = f >> 2, q = f & 3;
        w1r[f] = w1g[q * 4096 + ks * 64];
        pin4(w1r[f]);
    }
    #pragma unroll
    for (int fi = 0; fi < 5; ++fi) {
        int f = 27 + fi, ks = f >> 2, q = f & 3;
        wldsU[(w * 5 + fi) * 64 + l] = w1g[q * 4096 + ks * 64];
    }
    __syncthreads();

    float c0s[4] = {0.f, 0.f, 0.f, 0.f};
    float c1s[4] = {0.f, 0.f, 0.f, 0.f};

    for (int t = 0; t < TT; ++t) {
        _Float16* Ac = (t & 1) ? A1 : A0;
        _Float16* An = (t & 1) ? A0 : A1;
        const f16x8* apC = reinterpret_cast<const f16x8*>(Ac + lo16 * LDA);
        const f16x8* apN = reinterpret_cast<const f16x8*>(An + lo16 * LDA);

        // prefetch per-step inputs
        const float tfv = tf_rand[t * BB + b_base + om];
        float tgtv = 0.f;
        if (pl < OD) tgtv = target_seq[((b_base + om) * TT + t) * OD + pl];

        f32x4 acc[4];

        // ---- P0: z0 = cz + prev@Wp + h0old@Whh0 ----
        #pragma unroll
        for (int q = 0; q < 4; ++q)
            acc[q] = {(float)czp[q][0], (float)czp[q][1],
                      (float)czp[q][2], (float)czp[q][3]};
        #pragma unroll
        for (int r = 0; r < 4; ++r) {
            const float4 pv = *reinterpret_cast<const float4*>(prevs + (lhi * 4 + r) * 4);
            #pragma unroll
            for (int q = 0; q < 4; ++q)
                acc[q][r] = fmaf(pv.z, wprev[q][2],
                            fmaf(pv.y, wprev[q][1],
                            fmaf(pv.x, wprev[q][0], acc[q][r])));
        }
        #pragma unroll
        for (int ks = 0; ks < 4; ++ks) {
            const f16x8 a = apC[ks * 4 + lhi];
            #pragma unroll
            for (int q = 0; q < 4; ++q)
                acc[q] = __builtin_amdgcn_mfma_f32_16x16x32_f16(
                             a, __builtin_bit_cast(f16x8, w0r[ks * 4 + q]), acc[q], 0, 0, 0);
        }

        // ---- P1: gate-0 (lane-local), write h0new -> An ----
        #pragma unroll
        for (int r = 0; r < 4; ++r) {
            const float zi = acc[0][r], zf = acc[1][r], zg = acc[2][r], zo = acc[3][r];
            c0s[r] = sigf(zf) * c0s[r] + sigf(zi) * tanhfast(zg);
            An[(lhi * 4 + r) * LDA + w * 16 + lo16] = (_Float16)(sigf(zo) * tanhfast(c0s[r]));
        }
        __syncthreads();   // bar_a: h0new visible

        // ---- P2: z1 = b1 + [h0new ; h1old] @ W1 ----
        #pragma unroll
        for (int q = 0; q < 4; ++q) {
            const float bv = b1t[(w * 4 + q) * 16 + lo16];
            acc[q] = {bv, bv, bv, bv};
        }
        #pragma unroll
        for (int ks = 0; ks < 8; ++ks) {
            const f16x8 a = (ks < 4) ? apN[ks * 4 + lhi]
                                     : apC[16 + (ks - 4) * 4 + lhi];
            #pragma unroll
            for (int q = 0; q < 4; ++q) {
                const int f = ks * 4 + q;
                f16x8 b;
                if (f < 27) b = __builtin_bit_cast(f16x8, w1r[f]);
                else        b = __builtin_bit_cast(f16x8, wldsU[(w * 5 + (f - 27)) * 64 + l]);
                acc[q] = __builtin_amdgcn_mfma_f32_16x16x32_f16(a, b, acc[q], 0, 0, 0);
            }
        }

        // ---- P3: gate-1 (lane-local), write h1new -> An ----
        #pragma unroll
        for (int r = 0; r < 4; ++r) {
            const float zi = acc[0][r], zf = acc[1][r], zg = acc[2][r], zo = acc[3][r];
            c1s[r] = sigf(zf) * c1s[r] + sigf(zi) * tanhfast(zg);
            An[(lhi * 4 + r) * LDA + HH + w * 16 + lo16] = (_Float16)(sigf(zo) * tanhfast(c1s[r]));
        }
        __syncthreads();   // bar_b: h1new visible

        // ---- P4: output projection + teacher forcing ----
        {
            const f16x4 hv = *reinterpret_cast<const f16x4*>(An + om * LDA + HH + pl * 4);
            const float h0_ = (float)hv[0], h1_ = (float)hv[1],
                        h2_ = (float)hv[2], h3_ = (float)hv[3];
            const float4 wv0 = *reinterpret_cast<const float4*>(WoT + 0 * 128 + pl * 4);
            const float4 wv1 = *reinterpret_cast<const float4*>(WoT + 1 * 128 + pl * 4);
            const float4 wv2 = *reinterpret_cast<const float4*>(WoT + 2 * 128 + pl * 4);
            float s0 = fmaf(h3_, wv0.w, fmaf(h2_, wv0.z, fmaf(h1_, wv0.y, h0_ * wv0.x)));
            float s1 = fmaf(h3_, wv1.w, fmaf(h2_, wv1.z, fmaf(h1_, wv1.y, h0_ * wv1.x)));
            float s2 = fmaf(h3_, wv2.w, fmaf(h2_, wv2.z, fmaf(h1_, wv2.y, h0_ * wv2.x)));
            #pragma unroll
            for (int sh = 16; sh >= 1; sh >>= 1) {
                s0 += __shfl_xor(s0, sh, 32);
                s1 += __shfl_xor(s1, sh, 32);
                s2 += __shfl_xor(s2, sh, 32);
            }
            if (pl < OD) {
                const float sv = (pl == 0) ? s0 : (pl == 1) ? s1 : s2;
                const float pred = sv + bov;
                const int bg = b_base + om;
                out[(bg * TT + t) * OD + pl] = pred;
                const bool use_tf = (tfv < 0.5f) && (t < plen);
                prevs[om * 4 + pl] = use_tf ? tgtv : pred;
            }
        }
        __syncthreads();   // bar_c: prevs ready for next step
    }
}

extern "C" void kernel_launch(void* const* d_in, const int* in_sizes, int n_in,
                              void* d_out, int out_size, void* d_ws, size_t ws_size,
                              hipStream_t stream) {
    const float* conds   = (const float*)d_in[0];
    const float* target  = (const float*)d_in[1];
    const int*   lengths = (const int*)d_in[2];
    const float* tfr     = (const float*)d_in[3];
    const float* Wc      = (const float*)d_in[4];
    const float* bc      = (const float*)d_in[5];
    const float* Wih0    = (const float*)d_in[6];
    const float* Whh0    = (const float*)d_in[7];
    const float* b0      = (const float*)d_in[8];
    const float* Wih1    = (const float*)d_in[9];
    const float* Whh1    = (const float*)d_in[10];
    const float* b1      = (const float*)d_in[11];
    const float* Wo      = (const float*)d_in[12];
    const float* bo      = (const float*)d_in[13];
    float* out = (float*)d_out;
    _Float16* wf = (_Float16*)d_ws;

    repack_frag_kernel<<<WF_TOTAL / 256, 256, 0, stream>>>(Whh0, Wih1, Whh1, wf);
    dubins_lstm_mfma_kernel<<<BB / EPB, 512, 0, stream>>>(
        conds, target, lengths, tfr, Wc, bc,
        Wih0, b0, b1, Wo, bo, wf, out);
}